// Round 10
// baseline (105.313 us; speedup 1.0000x reference)
//
#include <hip/hip_runtime.h>
#include <math.h>

#define NN 50000
#define BB 32
#define KK 32
#define TN 64   // nodes per block in prep kernel
#define GN 8    // nodes per block in gather (NN % GN == 0 -> grid 6250)

// sqrt(log2(e)): all f-values carry this factor so sum(d^2) is in log2
// units -> exp2(-acc) == exp(-d2_true). (lrelu commutes with pos. scale.)
#define SCL 1.2011224087864498f
#define S0  (4096.0f / 12.0f)      // 12-bit quant scale over x range +-6

typedef __attribute__((ext_vector_type(2))) _Float16 half2_t;
typedef __attribute__((ext_vector_type(4))) _Float16 half4_t;

// ---- 64B/node row layout (line-aligned => ONE L2 line per gathered node):
//   dwords 0..7  : lo bytes of q[b] (b = 4d..4d+3 in dword d)
//   dwords 8..11 : hi nibbles, byte 32+i = hi(q[2i]) | hi(q[2i+1])<<4
//   dword 12     : f16 C0 | f16 C1      (C_j = SCL * g_j)
//   dword 13     : f16 C2 | 0
//   dwords 14,15 : pad
// q[b] = clamp(round(x[b]*S0) + 2048, 0, 4095).
// Dequant magic: as_float(0x46000000|q) = 8192 + q/1024 exactly; one fmaf
// recovers p = SCL*x (constant rounding bias in K2 cancels in fn - fm).

__device__ __forceinline__ half2_t dupc(half4_t v, int which) {
    if (which == 0) return __builtin_shufflevector(v, v, 0, 0);
    if (which == 1) return __builtin_shufflevector(v, v, 1, 1);
    return __builtin_shufflevector(v, v, 2, 2);
}

__device__ __forceinline__ half2_t pk2(float a, float b) {
#if __has_builtin(__builtin_amdgcn_cvt_pkrtz)
    return __builtin_bit_cast(half2_t, __builtin_amdgcn_cvt_pkrtz(a, b));
#else
    half2_t r; r.x = (_Float16)a; r.y = (_Float16)b; return r;
#endif
}

// Unpack 4 consecutive b's (lane's quartet) -> two half2 of p = SCL*x.
__device__ __forceinline__ void unpack4(unsigned int lod, unsigned int hiw,
                                        float K1, float K2,
                                        half2_t& p01, half2_t& p23) {
    unsigned int q0 = (lod & 0xFFu)         | ((hiw & 0x000Fu) << 8);
    unsigned int q1 = ((lod >> 8) & 0xFFu)  | ((hiw & 0x00F0u) << 4);
    unsigned int q2 = ((lod >> 16) & 0xFFu) | (((hiw >> 8) & 0xFu) << 8);
    unsigned int q3 = (lod >> 24)           | (((hiw >> 12) & 0xFu) << 8);
    float p0 = fmaf(__uint_as_float(0x46000000u | q0), K1, K2);
    float p1 = fmaf(__uint_as_float(0x46000000u | q1), K1, K2);
    float p2 = fmaf(__uint_as_float(0x46000000u | q2), K1, K2);
    float p3 = fmaf(__uint_as_float(0x46000000u | q3), K1, K2);
    p01 = pk2(p0, p1);
    p23 = pk2(p2, p3);
}

__global__ __launch_bounds__(256) void prep_kernel(
    const float* __restrict__ x,      // (B,N)
    const float* __restrict__ emb,    // (N,6)
    const float* __restrict__ W,      // (3,6)
    const float* __restrict__ bias,   // (3,)
    unsigned int* __restrict__ rows)  // (N,16) dwords
{
    __shared__ float xs[BB][TN + 1];          // transpose tile, pad->no conflict
    __shared__ unsigned short qs[TN][BB];     // 12-bit codes
    __shared__ unsigned int ch[TN][2];        // packed f16 C's

    const int n0 = blockIdx.x * TN;
    const int t  = threadIdx.x;

#pragma unroll
    for (int j = 0; j < 8; ++j) {
        int idx = j * 256 + t;        // 0..2047
        int r = idx >> 6, c = idx & 63;
        int n = n0 + c;
        xs[r][c] = (n < NN) ? x[r * NN + n] : 0.f;
    }
    __syncthreads();

#pragma unroll
    for (int it = 0; it < 4; ++it) {
        int slot = it * 256 + t;      // 0..1023: (node, b-pair)
        int nl = slot >> 4, b2 = slot & 15;
        int q0 = (int)rintf(xs[2 * b2][nl] * S0) + 2048;
        int q1 = (int)rintf(xs[2 * b2 + 1][nl] * S0) + 2048;
        q0 = q0 < 0 ? 0 : (q0 > 4095 ? 4095 : q0);
        q1 = q1 < 0 ? 0 : (q1 > 4095 ? 4095 : q1);
        qs[nl][2 * b2]     = (unsigned short)q0;
        qs[nl][2 * b2 + 1] = (unsigned short)q1;
        int n = n0 + nl;
        if (b2 == 0 && n < NN) {
            float e[6];
#pragma unroll
            for (int q = 0; q < 6; ++q) e[q] = emb[n * 6 + q];
            unsigned short cb[3];
#pragma unroll
            for (int j = 0; j < 3; ++j) {
                float s = bias[j];
#pragma unroll
                for (int q = 0; q < 6; ++q) s += e[q] * W[j * 6 + q];
                _Float16 h = (_Float16)(s * SCL);
                cb[j] = __builtin_bit_cast(unsigned short, h);
            }
            ch[nl][0] = (unsigned int)cb[0] | ((unsigned int)cb[1] << 16);
            ch[nl][1] = (unsigned int)cb[2];
        }
    }
    __syncthreads();

    // Emit rows: 16 dwords per node, coalesced.
#pragma unroll
    for (int it = 0; it < 4; ++it) {
        int slot = it * 256 + t;      // 0..1023: (node, dword)
        int nl = slot >> 4, d = slot & 15;
        int n = n0 + nl;
        if (n >= NN) continue;
        unsigned int w = 0;
        if (d < 8) {
            int b = 4 * d;
            w = ((unsigned int)(qs[nl][b] & 0xFF))
              | ((unsigned int)(qs[nl][b + 1] & 0xFF) << 8)
              | ((unsigned int)(qs[nl][b + 2] & 0xFF) << 16)
              | ((unsigned int)(qs[nl][b + 3] & 0xFF) << 24);
        } else if (d < 12) {
            int i0 = 8 * (d - 8);
#pragma unroll
            for (int i = 0; i < 8; ++i)
                w |= ((unsigned int)(qs[nl][i0 + i] >> 8)) << (4 * i);
        } else if (d == 12) {
            w = ch[nl][0];
        } else if (d == 13) {
            w = ch[nl][1];
        }
        rows[(size_t)n * 16 + d] = w;
    }
}

// Gather: block = 8 nodes (grid 6250). 32 subgroups of 8 lanes; subgroup
// sg owns node (sg>>2), k-range (sg&3)*8..+7; lane l holds b = 4l..4l+3.
// Per neighbor: lo dword + hi ushort + C half4 -- all in ONE 64B line
// (R8 touched 2 lines/pair; line count has tracked gather time all session).
__global__ __launch_bounds__(256) void gather_kernel(
    const unsigned int* __restrict__ rows,   // (N,16)
    const float* __restrict__ W,             // (3,6)
    const int* __restrict__ nbr,             // (N,K)
    float* __restrict__ out)                 // (N,K)
{
    __shared__ int nbr_sh[GN * KK];   // 256

    const int t  = threadIdx.x;
    const int n0 = blockIdx.x * GN;
    const unsigned short* rows16 = (const unsigned short*)rows;

    nbr_sh[t] = nbr[n0 * KK + t];
    __syncthreads();

    const float K1 = 1024.0f * SCL / S0;
    const float K2 = -8390656.0f * SCL / S0;  // -(8192*1024 + 2048)*SCL/S0

    half2_t wsh[3];
#pragma unroll
    for (int j = 0; j < 3; ++j) {
        float s = 0.f;
#pragma unroll
        for (int q = 0; q < 6; ++q) s += W[j * 6 + q];
        _Float16 h = (_Float16)s;
        wsh[j].x = h; wsh[j].y = h;
    }
    half2_t lk; lk.x = (_Float16)0.2f; lk.y = (_Float16)0.2f;

    const int l  = t & 7;             // lane in subgroup
    const int sg = t >> 3;            // 0..31
    const int nl = sg >> 2;           // node local 0..7
    const int kb = (sg & 3) * 8;      // k base
    const int n  = n0 + nl;

    // Center features: unpack own node once, keep 6 half2 in regs.
    half2_t fn01[3], fn23[3];
    {
        unsigned int lod = rows[(size_t)n * 16 + l];
        unsigned short hiw = rows16[(size_t)n * 32 + 16 + l];
        half4_t c4 = *(const half4_t*)(rows + (size_t)n * 16 + 12);
        half2_t p01, p23;
        unpack4(lod, hiw, K1, K2, p01, p23);
#pragma unroll
        for (int j = 0; j < 3; ++j) {
            half2_t g = dupc(c4, j);
            half2_t u = p01 * wsh[j] + g;
            fn01[j] = __builtin_elementwise_max(u, u * lk);
            u = p23 * wsh[j] + g;
            fn23[j] = __builtin_elementwise_max(u, u * lk);
        }
    }

    const int mb = nl * KK + kb;

#pragma unroll
    for (int i = 0; i < 8; ++i) {
        int m  = nbr_sh[mb + i];      // broadcast ds_read
        int mc = m > 0 ? m : 0;
        unsigned int lod = rows[(size_t)mc * 16 + l];
        unsigned short hiw = rows16[(size_t)mc * 32 + 16 + l];
        half4_t c4 = *(const half4_t*)(rows + (size_t)mc * 16 + 12);

        half2_t p01, p23;
        unpack4(lod, hiw, K1, K2, p01, p23);

        half2_t a01, a23;
        a01.x = (_Float16)0.f; a01.y = (_Float16)0.f;
        a23 = a01;
#pragma unroll
        for (int j = 0; j < 3; ++j) {
            half2_t g = dupc(c4, j);
            half2_t u = p01 * wsh[j] + g;
            u = __builtin_elementwise_max(u, u * lk);
            half2_t d = fn01[j] - u;
            a01 = d * d + a01;
            u = p23 * wsh[j] + g;
            u = __builtin_elementwise_max(u, u * lk);
            d = fn23[j] - u;
            a23 = d * d + a23;
        }
        float v = (exp2f(-(float)a01.x) + exp2f(-(float)a01.y))
                + (exp2f(-(float)a23.x) + exp2f(-(float)a23.y));
        v += __shfl_down(v, 4, 8);
        v += __shfl_down(v, 2, 8);
        v += __shfl_down(v, 1, 8);
        if (l == 0) out[n * KK + kb + i] = (m < 0) ? 0.f : v * (1.0f / 32.0f);
    }
}

extern "C" void kernel_launch(void* const* d_in, const int* in_sizes, int n_in,
                              void* d_out, int out_size, void* d_ws, size_t ws_size,
                              hipStream_t stream) {
    const float* x    = (const float*)d_in[0];
    const float* emb  = (const float*)d_in[1];
    const float* W    = (const float*)d_in[2];
    const float* bias = (const float*)d_in[3];
    const int*   nbr  = (const int*)d_in[4];
    float* out = (float*)d_out;

    unsigned int* rows = (unsigned int*)d_ws;   // N*64B = 3.2 MB

    prep_kernel<<<(NN + TN - 1) / TN, 256, 0, stream>>>(x, emb, W, bias, rows);
    gather_kernel<<<NN / GN, 256, 0, stream>>>(rows, W, nbr, out);
}

// Round 11
// 100.041 us; speedup vs baseline: 1.0527x; 1.0527x over previous
//
#include <hip/hip_runtime.h>
#include <math.h>

#define NN 50000
#define BB 32
#define KK 32
#define TN 64   // nodes per block in prep kernel
#define GN 8    // nodes per block in gather kernel (NN % GN == 0)

// sqrt(log2(e)): ws,g carry this factor so sum(d^2) is already in log2
// units -> exp2(-acc) == exp(-d2_true). (lrelu commutes with pos. scale.)
#define SCL 1.2011224087864498f

typedef __attribute__((ext_vector_type(2))) _Float16 half2_t;
typedef __attribute__((ext_vector_type(4))) _Float16 half4_t;
typedef __attribute__((ext_vector_type(8))) _Float16 half8_t;

// __builtin_shufflevector needs literal indices -> hand-unrolled extractors.
__device__ __forceinline__ half4_t g_dup0(half8_t v) {
    return __builtin_shufflevector(v, v, 0, 1, 0, 1);
}
__device__ __forceinline__ half4_t g_dup1(half8_t v) {
    return __builtin_shufflevector(v, v, 2, 3, 2, 3);
}
__device__ __forceinline__ half4_t g_dup2(half8_t v) {
    return __builtin_shufflevector(v, v, 4, 5, 4, 5);
}

// Prep: store what gather needs to RECOMPUTE f on the fly, in fp16:
//   xT[n][b2] = half2(x[2b2,n], x[2b2+1,n])         (64 B/node row)
//   gh[n]     = half8: dwords = (G0,G0),(G1,G1),(G2,G2),(0,0), G=SCL*g
// g[j] = sum_e emb[n,e]*W[j,e] + bias[j]. Random-gather working set:
// 3.2 + 0.8 = 4 MB (L2-resident; 12.8MB variant spilled -> 147MB fetch, R2).
// Gather is at the recompute VALU floor (~30us): 15 pk-insts per b-pair
// is irreducible for lrelu-recompute; stored-f alternatives need >=192B/node
// rows -> spill L2 -> fabric-bound (R2: 83us). R8/R10 confirmed inst- and
// line-count tweaks are neutral/negative around this floor.
__global__ __launch_bounds__(256) void prep_kernel(
    const float* __restrict__ x,      // (B,N)
    const float* __restrict__ emb,    // (N,6)
    const float* __restrict__ W,      // (3,6)
    const float* __restrict__ bias,   // (3,)
    half2_t* __restrict__ xT,         // (N,16)
    half8_t* __restrict__ gh)         // (N)
{
    __shared__ float xs[BB][TN + 1];  // +1 pad: transpose read conflict-free

    const int n0 = blockIdx.x * TN;
    const int t  = threadIdx.x;

#pragma unroll
    for (int j = 0; j < 8; ++j) {
        int idx = j * 256 + t;        // 0..2047
        int r = idx >> 6, c = idx & 63;
        int n = n0 + c;
        xs[r][c] = (n < NN) ? x[r * NN + n] : 0.f;
    }
    __syncthreads();

#pragma unroll
    for (int it = 0; it < 4; ++it) {
        int slot = it * 256 + t;      // 0..1023
        int nl = slot >> 4, b2 = slot & 15;
        int n = n0 + nl;
        if (n < NN) {
            half2_t p;
            p.x = (_Float16)(xs[2 * b2][nl] * SCL);
            p.y = (_Float16)(xs[2 * b2 + 1][nl] * SCL);
            xT[n * 16 + b2] = p;                // 16 lanes -> 64B contiguous
            if (b2 == 0) {
                float e[6];
#pragma unroll
                for (int q = 0; q < 6; ++q) e[q] = emb[n * 6 + q];
                half8_t gv;
#pragma unroll
                for (int j = 0; j < 3; ++j) {
                    float s = bias[j];
#pragma unroll
                    for (int q = 0; q < 6; ++q) s += e[q] * W[j * 6 + q];
                    s *= SCL;
                    gv[2 * j] = (_Float16)s;
                    gv[2 * j + 1] = (_Float16)s;
                }
                gv[6] = (_Float16)0.f; gv[7] = (_Float16)0.f;
                gh[n] = gv;
            }
        }
    }
}

// Gather: block = 8 nodes (grid 6250). 32 subgroups of 8 lanes; subgroup
// sg owns node (sg>>2) and k-range (sg&3)*8..+7, lane l holds b = 4l..4l+3
// as one half4. fn in registers (computed once per subgroup); 8 unrolled
// k-iterations keep 16 independent loads in flight. NOTE: xT holds SCL*x
// (prep pre-scales), so ws here is UNscaled -- product carries exactly one
// SCL and acc is in log2 units for exp2.
__global__ __launch_bounds__(256) void gather_kernel(
    const half4_t* __restrict__ xT4,  // (N,8) viewed as half4 (SCL-scaled x)
    const half8_t* __restrict__ gh,   // (N)  (SCL-scaled g)
    const float* __restrict__ W,      // (3,6)
    const int* __restrict__ nbr,      // (N,K)
    float* __restrict__ out)          // (N,K)
{
    __shared__ int nbr_sh[GN * KK];   // 8 nodes x 32 k

    const int t  = threadIdx.x;
    const int n0 = blockIdx.x * GN;

    nbr_sh[t] = nbr[n0 * KK + t];
    __syncthreads();

    // ws[j] = sum_e W[j,e] (unscaled; SCL lives in xT/gh).
    half4_t ws4[3];
#pragma unroll
    for (int j = 0; j < 3; ++j) {
        float s = 0.f;
#pragma unroll
        for (int q = 0; q < 6; ++q) s += W[j * 6 + q];
        _Float16 h = (_Float16)s;
        ws4[j].x = h; ws4[j].y = h; ws4[j].z = h; ws4[j].w = h;
    }
    half4_t lk;
    lk.x = (_Float16)0.2f; lk.y = (_Float16)0.2f;
    lk.z = (_Float16)0.2f; lk.w = (_Float16)0.2f;

    const int l  = t & 7;             // lane in subgroup
    const int sg = t >> 3;            // 0..31
    const int nl = sg >> 2;           // node local 0..7
    const int kg = (sg & 3) * 8;      // k base
    const int n  = n0 + nl;

    // Center features for this lane's 4 b's (registers, once per subgroup).
    half4_t xn4 = xT4[n * 8 + l];     // 8B/lane, 64B/row coalesced
    half8_t gn8 = gh[n];
    half4_t fn[3];
    {
        half4_t u0 = xn4 * ws4[0] + g_dup0(gn8);
        fn[0] = __builtin_elementwise_max(u0, u0 * lk);
        half4_t u1 = xn4 * ws4[1] + g_dup1(gn8);
        fn[1] = __builtin_elementwise_max(u1, u1 * lk);
        half4_t u2 = xn4 * ws4[2] + g_dup2(gn8);
        fn[2] = __builtin_elementwise_max(u2, u2 * lk);
    }

    const int mbase = nl * KK + kg;   // nbr_sh base for this subgroup

#pragma unroll
    for (int i = 0; i < 8; ++i) {
        int m  = nbr_sh[mbase + i];   // broadcast ds_read, imm offset
        int mc = m > 0 ? m : 0;
        half4_t xm4 = xT4[mc * 8 + l];          // 8B/lane
        half8_t gm8 = gh[mc];                   // 16B broadcast per subgroup

        half4_t acc;
        acc.x = (_Float16)0.f; acc.y = (_Float16)0.f;
        acc.z = (_Float16)0.f; acc.w = (_Float16)0.f;
        {
            half4_t u, d;
            u = xm4 * ws4[0] + g_dup0(gm8);
            u = __builtin_elementwise_max(u, u * lk);
            d = fn[0] - u; acc = d * d + acc;
            u = xm4 * ws4[1] + g_dup1(gm8);
            u = __builtin_elementwise_max(u, u * lk);
            d = fn[1] - u; acc = d * d + acc;
            u = xm4 * ws4[2] + g_dup2(gm8);
            u = __builtin_elementwise_max(u, u * lk);
            d = fn[2] - u; acc = d * d + acc;
        }
        // acc in log2 units (SCL^2 folded into xT/gh) -> plain exp2.
        float v = (exp2f(-(float)acc.x) + exp2f(-(float)acc.y))
                + (exp2f(-(float)acc.z) + exp2f(-(float)acc.w));
        v += __shfl_down(v, 4, 8);
        v += __shfl_down(v, 2, 8);
        v += __shfl_down(v, 1, 8);
        if (l == 0) out[n * KK + kg + i] = (m < 0) ? 0.f : v * (1.0f / 32.0f);
    }
}

extern "C" void kernel_launch(void* const* d_in, const int* in_sizes, int n_in,
                              void* d_out, int out_size, void* d_ws, size_t ws_size,
                              hipStream_t stream) {
    const float* x    = (const float*)d_in[0];
    const float* emb  = (const float*)d_in[1];
    const float* W    = (const float*)d_in[2];
    const float* bias = (const float*)d_in[3];
    const int*   nbr  = (const int*)d_in[4];
    float* out = (float*)d_out;

    half2_t* xT = (half2_t*)d_ws;                              // 3.2 MB
    half8_t* gh = (half8_t*)((char*)d_ws + NN * 16 * sizeof(half2_t)); // 0.8 MB

    prep_kernel<<<(NN + TN - 1) / TN, 256, 0, stream>>>(x, emb, W, bias, xT, gh);
    gather_kernel<<<NN / GN, 256, 0, stream>>>((const half4_t*)xT, gh, W, nbr, out);
}